// Round 1
// baseline (9.692 us; speedup 1.0000x reference)
//
#include <hip/hip_runtime.h>

// P1 hat-function space evaluation on a structured 32x32 grid mesh.
// Inputs (dict order): x[B,N,2] f32, weight[1024] f32, Tinv[1024,6,2,2] f32,
//                      b[1024,6,2] f32, bbox[1024,4] f32, mask[1024,6] bool (UNUSED —
//                      derived from Tinv==0 to avoid bool-dtype layout ambiguity).
// Output: [B,N] f32 (8192 elems).
//
// Key insight: vertex (i,j) at (i/31, j/31) has patch bbox within
// [(i-1)/31,(i+1)/31] x [(j-1)/31,(j+1)/31]; only a 4x4 vertex window around
// the point can pass the reference's in_bbox test. All other vertices give
// exactly 0 (bbox test fails), matching the reference's dense computation.

#define NGRID 32
#define KMAX  6

__global__ __launch_bounds__(256) void p1_eval_kernel(
    const float* __restrict__ x,     // [P,2]
    const float* __restrict__ w,     // [1024]
    const float* __restrict__ Tinv,  // [1024,6,2,2]
    const float* __restrict__ bvec,  // [1024,6,2]
    const float* __restrict__ bbox,  // [1024,4]
    float* __restrict__ out,         // [P]
    int P)
{
    const int tid  = blockIdx.x * blockDim.x + threadIdx.x;
    const int p    = tid >> 4;   // point index
    const int cand = tid & 15;   // candidate vertex in 4x4 window

    float acc = 0.0f;
    if (p < P) {
        const float x0 = x[2 * p];
        const float x1 = x[2 * p + 1];

        const int ci = (int)floorf(x0 * 31.0f);
        const int cj = (int)floorf(x1 * 31.0f);
        const int i  = ci + (cand >> 2) - 1;
        const int j  = cj + (cand & 3) - 1;

        if (i >= 0 && i < NGRID && j >= 0 && j < NGRID) {
            const int v = i * NGRID + j;
            const float4 bb = reinterpret_cast<const float4*>(bbox)[v];
            const float TOL = 1e-8f;
            if ((bb.x - TOL < x0) && (x0 < bb.y + TOL) &&
                (bb.z - TOL < x1) && (x1 < bb.w + TOL)) {
                float hat = INFINITY;
                #pragma unroll
                for (int k = 0; k < KMAX; ++k) {
                    // Tinv[v][k] row-major: {t00, t01, t10, t11}, t[j][i]
                    const float4 t = reinterpret_cast<const float4*>(Tinv)[v * KMAX + k];
                    const bool valid = (t.x != 0.0f) || (t.y != 0.0f) ||
                                       (t.z != 0.0f) || (t.w != 0.0f);
                    if (valid) {
                        const float2 bk = reinterpret_cast<const float2*>(bvec)[v * KMAX + k];
                        const float y0 = x0 * t.x + x1 * t.z + bk.x;
                        const float y1 = x0 * t.y + x1 * t.w + bk.y;
                        const float val = fmaxf(1.0f - y0 - y1, 0.0f);
                        hat = fminf(hat, val);
                    }
                }
                acc = hat * w[v];
            }
        }
    }

    // Reduce the 16 candidate lanes (16 consecutive lanes share one point).
    acc += __shfl_xor(acc, 1, 64);
    acc += __shfl_xor(acc, 2, 64);
    acc += __shfl_xor(acc, 4, 64);
    acc += __shfl_xor(acc, 8, 64);

    if (p < P && cand == 0) out[p] = acc;
}

extern "C" void kernel_launch(void* const* d_in, const int* in_sizes, int n_in,
                              void* d_out, int out_size, void* d_ws, size_t ws_size,
                              hipStream_t stream) {
    const float* x    = (const float*)d_in[0];  // [B,N,2]
    const float* w    = (const float*)d_in[1];  // [1024]
    const float* Tinv = (const float*)d_in[2];  // [1024,6,2,2]
    const float* bvec = (const float*)d_in[3];  // [1024,6,2]
    const float* bbox = (const float*)d_in[4];  // [1024,4]
    // d_in[5] = mask (bool) — intentionally unused; derived from Tinv == 0.

    float* out = (float*)d_out;
    const int P = in_sizes[0] / 2;  // B*N points

    const int threads = 256;
    const int total   = P * 16;    // one thread per (point, candidate)
    const int blocks  = (total + threads - 1) / threads;
    p1_eval_kernel<<<blocks, threads, 0, stream>>>(x, w, Tinv, bvec, bbox, out, P);
}